// Round 3
// baseline (100.408 us; speedup 1.0000x reference)
//
#include <hip/hip_runtime.h>
#include <math.h>

// GMM score, rescaled: out_j = (E_w[td] - x_j) / sigma2_j
// w_i = exp(-0.5 (td_i - x_j)^2 / sigma2_j), sigma2_j = (exp(2 t_j ln25)-1)/(2 ln25)
//
// B = N = 16384, d = 1. VALU-issue-bound (268M exp evals).
// R3 changes vs R2:
//  - S=32 -> 2048 blocks = 8 blocks/CU: restores occupancy (R2's S=16 dropped
//    VALUBusy to 65% -- exp latency exposed at 4 blocks/CU)
//  - 4 pk-instr inner form: d = fma(td, r, -x*r); q = d*d; exp2(-q) with the
//    negate folded into v_exp_f32's input modifier (r = sqrt(0.5*log2e)/sigma
//    hoisted per j). Was 5 pk-instrs (sub, mul, mul, add, fma).
//  - 8-elem unrolled body: 8 independent exp chains per thread for ILP.

typedef float v2f __attribute__((ext_vector_type(2)));

#define BLK   256
#define CH    512    // train elements per slice (2 KB LDS)

#if __has_builtin(__builtin_amdgcn_exp2f)
#define EXP2(x) __builtin_amdgcn_exp2f(x)
#else
#define EXP2(x) exp2f(x)
#endif

__device__ __forceinline__ float sigma2_of(float tj) {
  const float TWO_LOG_S = 6.4377516497364011f;   // 2*ln(25)
  return (__expf(TWO_LOG_S * tj) - 1.0f) / TWO_LOG_S;
}

template <bool ATOMIC>
__launch_bounds__(BLK)
__global__ void gmm_partial(const float* __restrict__ x,
                            const float* __restrict__ t,
                            const float* __restrict__ td,
                            float* __restrict__ ws,
                            int N, int B) {
  __shared__ float lds[CH];
  const int tid  = threadIdx.x;
  const int j    = blockIdx.x * BLK + tid;   // output index
  const int s    = blockIdx.y;               // N-slice
  const int S    = gridDim.y;
  const int base = s * CH;

  for (int i = tid; i < CH; i += BLK) {
    int gi = base + i;
    // pad -> d^2 = inf -> exp2(-inf) = 0 (weightless)
    lds[i] = (gi < N) ? td[gi] : 1e30f;
  }

  float r = 0.0f, y = 0.0f;
  if (j < B) {
    const float HALF_LOG2E = 0.72134752044448170f;  // 0.5 * log2(e)
    float s2 = sigma2_of(t[j]);
    r = __fsqrt_rn(HALF_LOG2E / s2);   // d_scaled = (td - x)*r ; arg = -d^2
    y = x[j] * r;
  }
  __syncthreads();

  const v2f rv  = {r, r};
  const v2f nyv = {-y, -y};
  v2f num0 = {0.f, 0.f}, num1 = {0.f, 0.f}, num2 = {0.f, 0.f}, num3 = {0.f, 0.f};
  v2f den0 = {0.f, 0.f}, den1 = {0.f, 0.f}, den2 = {0.f, 0.f}, den3 = {0.f, 0.f};

  const float4* l4 = (const float4*)lds;   // ds_read_b128 broadcast, conflict-free
  const int iters = CH >> 3;               // 8 elements per iteration
  #pragma unroll 2
  for (int i = 0; i < iters; ++i) {
    float4 v0 = l4[2 * i];
    float4 v1 = l4[2 * i + 1];
    v2f va = {v0.x, v0.y}, vb = {v0.z, v0.w};
    v2f vc = {v1.x, v1.y}, vd = {v1.z, v1.w};
    // d = td*r - x*r   (one v_pk_fma_f32)
    v2f da = __builtin_elementwise_fma(va, rv, nyv);
    v2f db = __builtin_elementwise_fma(vb, rv, nyv);
    v2f dc = __builtin_elementwise_fma(vc, rv, nyv);
    v2f dd = __builtin_elementwise_fma(vd, rv, nyv);
    v2f qa = da * da;   // v_pk_mul_f32
    v2f qb = db * db;
    v2f qc = dc * dc;
    v2f qd = dd * dd;
    v2f pa, pb, pc, pd;
    pa.x = EXP2(-qa.x); pa.y = EXP2(-qa.y);   // v_exp_f32 with neg input mod
    pb.x = EXP2(-qb.x); pb.y = EXP2(-qb.y);
    pc.x = EXP2(-qc.x); pc.y = EXP2(-qc.y);
    pd.x = EXP2(-qd.x); pd.y = EXP2(-qd.y);
    den0 += pa;                                       // v_pk_add_f32
    den1 += pb;
    den2 += pc;
    den3 += pd;
    num0 = __builtin_elementwise_fma(pa, va, num0);   // v_pk_fma_f32
    num1 = __builtin_elementwise_fma(pb, vb, num1);
    num2 = __builtin_elementwise_fma(pc, vc, num2);
    num3 = __builtin_elementwise_fma(pd, vd, num3);
  }
  v2f numv = (num0 + num1) + (num2 + num3);
  v2f denv = (den0 + den1) + (den2 + den3);
  float num = numv.x + numv.y;
  float den = denv.x + denv.y;

  if (j < B) {
    if (ATOMIC) {
      atomicAdd(&ws[j], num);
      atomicAdd(&ws[B + j], den);
    } else {
      ws[(size_t)s * B + j]       = num;   // num partials: [S][B]
      ws[(size_t)(S + s) * B + j] = den;   // den partials: [S][B]
    }
  }
}

__global__ void gmm_final(const float* __restrict__ x,
                          const float* __restrict__ t,
                          const float* __restrict__ ws,
                          float* __restrict__ out, int B, int S) {
  int j = blockIdx.x * blockDim.x + threadIdx.x;
  if (j >= B) return;
  float num = 0.f, den = 0.f;
  for (int s = 0; s < S; ++s) {
    num += ws[(size_t)s * B + j];
    den += ws[(size_t)(S + s) * B + j];
  }
  float sigma2 = sigma2_of(t[j]);
  float evals = (den == 0.0f) ? 0.0f : (num / den);   // reference's den==0 guard
  out[j] = (evals - x[j]) / sigma2;
}

__global__ void zero_kernel(float* __restrict__ p, int n) {
  int i = blockIdx.x * blockDim.x + threadIdx.x;
  if (i < n) p[i] = 0.0f;
}

extern "C" void kernel_launch(void* const* d_in, const int* in_sizes, int n_in,
                              void* d_out, int out_size, void* d_ws, size_t ws_size,
                              hipStream_t stream) {
  const float* x  = (const float*)d_in[0];
  const float* t  = (const float*)d_in[1];
  const float* td = (const float*)d_in[2];
  float* out = (float*)d_out;
  float* ws  = (float*)d_ws;

  const int B = in_sizes[0];
  const int N = in_sizes[2];

  const int S = (N + CH - 1) / CH;                  // 32 for N=16384
  size_t need = (size_t)2 * S * B * sizeof(float);  // 4 MB

  if (ws_size >= need) {
    dim3 grid((B + BLK - 1) / BLK, S);              // (64, 32) = 2048 blocks
    gmm_partial<false><<<grid, BLK, 0, stream>>>(x, t, td, ws, N, B);
    gmm_final<<<(B + BLK - 1) / BLK, BLK, 0, stream>>>(x, t, ws, out, B, S);
  } else {
    // Fallback: zero + atomic accumulate + final (3 dispatches)
    int nzero = 2 * B;
    zero_kernel<<<(nzero + 255) / 256, 256, 0, stream>>>(ws, nzero);
    dim3 grid((B + BLK - 1) / BLK, S);
    gmm_partial<true><<<grid, BLK, 0, stream>>>(x, t, td, ws, N, B);
    gmm_final<<<(B + BLK - 1) / BLK, BLK, 0, stream>>>(x, t, ws, out, B, 1);
  }
}